// Round 1
// 65.267 us; speedup vs baseline: 1.0601x; 1.0601x over previous
//
#include <hip/hip_runtime.h>
#include <math.h>

// PlaceCellNetwork: C=4, B=2048, IN=64, OUT=128, 100 fixed-point iterations.
//
// With M == I (the actual input), the iteration collapses in closed form:
//   y_final = max(P_100*wx + Q_100 - P_100*b, 0)   exactly.
//
// Round-6 restructure: speculative fast-path + deferred verification.
//   - pcn_fast: per-block ONE-ROW M==I slice check (32 lanes, 1 uint4 each;
//     512 blocks <-> 4x128 rows, exact positional coverage) -> flag in d_ws,
//     then unconditionally computes the closed form via MFMA and stores.
//     No LDS, no __syncthreads, straight-line. Removes the ~250-VALU +
//     16-load redundant full-M check (>50% of issue) from every thread.
//   - pcn_fix: aggregates the 128 flags per c; clean -> immediate return
//     (out already correct); dirty -> full general-path recompute (exact
//     fallback preserved).
// MFMA: mfma_f32_16x16x32_bf16, 2-term Dekker split (hi=trunc bf16,
// lo=x-hi), 3 products. Verified layouts (learn_hip m89/m91/m120).

#define C_ 4
#define IN_ 64
#define OUT_ 128
#define B_ 2048
#define MAXITER_ 100
#define LBD1_ 0.005f
#define LBD2_ 0.005f

#define THREADS_ 256
#define ROWS_PER_BLOCK_ 16   // one 16-row M-tile per block; 4 waves x 32 cols

typedef short bf16x8 __attribute__((ext_vector_type(8)));   // 8 bf16 bit-patterns
typedef float f32x4  __attribute__((ext_vector_type(4)));

struct Frag2 { bf16x8 hi, lo; };

// Split 8 consecutive fp32 into (hi, lo) bf16x8 fragments.
// hi = truncate-to-bf16(x); lo = truncate-to-bf16(x - hi)  (x - hi is exact).
__device__ inline Frag2 split8(float4 a, float4 b)
{
    float xs[8] = {a.x, a.y, a.z, a.w, b.x, b.y, b.z, b.w};
    union { unsigned u[4]; bf16x8 v; } H, L;
    #pragma unroll
    for (int d = 0; d < 4; ++d) {
        float x0 = xs[2 * d], x1 = xs[2 * d + 1];
        unsigned u0 = __float_as_uint(x0), u1 = __float_as_uint(x1);
        float h0 = __uint_as_float(u0 & 0xFFFF0000u);
        float h1 = __uint_as_float(u1 & 0xFFFF0000u);
        float l0 = x0 - h0;
        float l1 = x1 - h1;
        // pack top halves of (u0,u1) -> one dword (low16 from u0)
        H.u[d] = __builtin_amdgcn_perm(u1, u0, 0x07060302u);
        L.u[d] = __builtin_amdgcn_perm(__float_as_uint(l1), __float_as_uint(l0),
                                       0x07060302u);
    }
    Frag2 f; f.hi = H.v; f.lo = L.v; return f;
}

// ---------------------------------------------------------------------------
// Kernel 1: speculative closed form + one-row M slice check.
// ---------------------------------------------------------------------------
__global__ __launch_bounds__(THREADS_)
void pcn_fast(const float* __restrict__ X,
              const float* __restrict__ W,
              const float* __restrict__ M,
              const float* __restrict__ bvec,
              float* __restrict__ out,
              unsigned* __restrict__ slots,
              float Pc, float Qc)
{
    const int tid   = threadIdx.x;
    const int bx    = blockIdx.x;
    const int c     = bx >> 7;          // 128 chunks per c
    const int chunk = bx & 127;
    const int wv    = tid >> 6;         // wave 0..3
    const int lane  = tid & 63;
    const int ln16  = lane & 15;        // m-index for A, n-index for B/D-col
    const int q     = lane >> 4;        // quad 0..3
    const int ob    = 32 * wv;          // wave's output-column base
    const int row0  = chunk * ROWS_PER_BLOCK_;

    const float* Wc = W + c * (OUT_ * IN_);

    // ---- raw fragment loads (issued first; all native-layout global) -------
    //  A: X[row0+ln16][q*8 + kk*32 + 0..7]   (2 kk-chunks x 2 float4)
    //  B: W[ob+16t+ln16][q*8 + kk*32 + 0..7] (2 tiles x 2 kk x 2 float4)
    const float* Xr = X + (row0 + ln16) * IN_ + q * 8;
    float4 ax[2][2], bw[2][2][2];
    #pragma unroll
    for (int kk = 0; kk < 2; ++kk) {
        ax[kk][0] = *(const float4*)(Xr + 32 * kk);
        ax[kk][1] = *(const float4*)(Xr + 32 * kk + 4);
    }
    #pragma unroll
    for (int t = 0; t < 2; ++t) {
        const float* Wr = Wc + (ob + 16 * t + ln16) * IN_ + q * 8;
        #pragma unroll
        for (int kk = 0; kk < 2; ++kk) {
            bw[t][kk][0] = *(const float4*)(Wr + 32 * kk);
            bw[t][kk][1] = *(const float4*)(Wr + 32 * kk + 4);
        }
    }

    // ---- one-row M slice check: this block verifies row `chunk` of M_c ----
    // 32 lanes x uint4 = 128 words = the full row. Expected: K at col==chunk.
    unsigned bad = 0;
    if (tid < 32) {
        const uint4* mrow =
            (const uint4*)(M + (size_t)c * (OUT_ * OUT_) + chunk * OUT_) + tid;
        uint4 v = *mrow;
        int e = chunk - 4 * tid;
        bad  = v.x ^ ((e == 0) ? 0x3F800000u : 0u);
        bad |= v.y ^ ((e == 1) ? 0x3F800000u : 0u);
        bad |= v.z ^ ((e == 2) ? 0x3F800000u : 0u);
        bad |= v.w ^ ((e == 3) ? 0x3F800000u : 0u);
    }
    unsigned long long bb = __ballot(bad != 0u);   // wave0 carries the result
    if (tid == 0) slots[bx] = (bb != 0ull) ? 1u : 0u;

    // ---- split to bf16 hi/lo fragments -------------------------------------
    Frag2 Af[2];
    #pragma unroll
    for (int kk = 0; kk < 2; ++kk) Af[kk] = split8(ax[kk][0], ax[kk][1]);
    Frag2 Bf[2][2];
    #pragma unroll
    for (int t = 0; t < 2; ++t)
        #pragma unroll
        for (int kk = 0; kk < 2; ++kk)
            Bf[t][kk] = split8(bw[t][kk][0], bw[t][kk][1]);

    // ---- MFMA: wx tiles (hi*hi + hi*lo + lo*hi) ----------------------------
    f32x4 acc[2];
    acc[0] = (f32x4){0.f, 0.f, 0.f, 0.f};
    acc[1] = (f32x4){0.f, 0.f, 0.f, 0.f};
    #pragma unroll
    for (int t = 0; t < 2; ++t) {
        #pragma unroll
        for (int kk = 0; kk < 2; ++kk) {
            acc[t] = __builtin_amdgcn_mfma_f32_16x16x32_bf16(
                         Af[kk].hi, Bf[t][kk].hi, acc[t], 0, 0, 0);
            acc[t] = __builtin_amdgcn_mfma_f32_16x16x32_bf16(
                         Af[kk].hi, Bf[t][kk].lo, acc[t], 0, 0, 0);
            acc[t] = __builtin_amdgcn_mfma_f32_16x16x32_bf16(
                         Af[kk].lo, Bf[t][kk].hi, acc[t], 0, 0, 0);
        }
    }

    // ---- closed-form epilogue: y = max(P*wx + (Q - P*b), 0) ----------------
    #pragma unroll
    for (int t = 0; t < 2; ++t) {
        float bt = bvec[c * OUT_ + ob + 16 * t + ln16];
        float gb = fmaf(-Pc, bt, Qc);     // Qc - Pc*b
        #pragma unroll
        for (int r = 0; r < 4; ++r) {
            int m = q * 4 + r;                    // output row within tile
            float y = fmaxf(fmaf(Pc, acc[t][r], gb), 0.0f);
            out[(c * B_ + row0 + m) * OUT_ + ob + 16 * t + ln16] = y;
        }
    }
}

// ---------------------------------------------------------------------------
// Kernel 2: verify flags; clean -> return (out already correct).
// Dirty -> exact general-path recompute (never taken for harness inputs).
// ---------------------------------------------------------------------------
__global__ __launch_bounds__(THREADS_)
void pcn_fix(const float* __restrict__ X,
             const float* __restrict__ W,
             const float* __restrict__ M,
             const float* __restrict__ bvec,
             float* __restrict__ out,
             const unsigned* __restrict__ slots)
{
    __shared__ float Ylds[ROWS_PER_BLOCK_ * OUT_];
    __shared__ unsigned sb[4];

    const int tid   = threadIdx.x;
    const int bx    = blockIdx.x;
    const int c     = bx >> 7;
    const int chunk = bx & 127;
    const int wv    = tid >> 6;
    const int lane  = tid & 63;
    const int ln16  = lane & 15;
    const int q     = lane >> 4;
    const int ob    = 32 * wv;
    const int row0  = chunk * ROWS_PER_BLOCK_;

    // aggregate the 128 per-row flags of this c
    unsigned my = (tid < 128) ? slots[c * 128 + tid] : 0u;
    unsigned long long wb = __ballot(my != 0u);
    if (lane == 0) sb[wv] = (wb != 0ull) ? 1u : 0u;
    __syncthreads();
    if ((sb[0] | sb[1] | sb[2] | sb[3]) == 0u) return;   // M == I: done.

    // ---- general path: exact fixed-point iteration -------------------------
    const float* Mc = M + (size_t)c * (OUT_ * OUT_);
    const float* Wc = W + c * (OUT_ * IN_);

    int   nt[2];
    float bt[2], dinvv[2];
    #pragma unroll
    for (int t = 0; t < 2; ++t) {
        nt[t]    = ob + 16 * t + ln16;
        bt[t]    = bvec[c * OUT_ + nt[t]];
        dinvv[t] = 1.0f / (LBD2_ + Mc[nt[t] * OUT_ + nt[t]]);
    }

    // wx via plain fp32 dot products (correctness-only path)
    float wxb[2][4], y[2][4];
    #pragma unroll
    for (int t = 0; t < 2; ++t) {
        const float* Wr = Wc + nt[t] * IN_;
        #pragma unroll
        for (int r = 0; r < 4; ++r) {
            const float* Xr = X + (row0 + q * 4 + r) * IN_;
            float s = 0.f;
            for (int k = 0; k < IN_; ++k) s = fmaf(Xr[k], Wr[k], s);
            wxb[t][r] = s - bt[t];
            y[t][r]   = 0.f;
        }
    }

    for (int it = 0; it < MAXITER_; ++it) {
        float dt = fmaxf(0.05f / (1.0f + (float)it / 10.0f), 0.01f);
        #pragma unroll
        for (int t = 0; t < 2; ++t)
            #pragma unroll
            for (int r = 0; r < 4; ++r)
                Ylds[(q * 4 + r) * OUT_ + nt[t]] = y[t][r];
        __syncthreads();
        float my2[2][4] = {{0.f,0.f,0.f,0.f},{0.f,0.f,0.f,0.f}};
        for (int o = 0; o < OUT_; ++o) {
            float mo[2];
            #pragma unroll
            for (int t = 0; t < 2; ++t)
                mo[t] = Mc[nt[t] * OUT_ + o] - (o == nt[t] ? 1.0f : 0.0f);
            #pragma unroll
            for (int r = 0; r < 4; ++r) {
                float yo = Ylds[(q * 4 + r) * OUT_ + o];
                my2[0][r] = fmaf(yo, mo[0], my2[0][r]);
                my2[1][r] = fmaf(yo, mo[1], my2[1][r]);
            }
        }
        #pragma unroll
        for (int t = 0; t < 2; ++t)
            #pragma unroll
            for (int r = 0; r < 4; ++r) {
                float uy = fmaf(dt, wxb[t][r] - y[t][r] - my2[t][r], y[t][r]);
                y[t][r] = fmaxf((uy - LBD1_) * dinvv[t], 0.0f);
            }
        __syncthreads();
    }
    #pragma unroll
    for (int t = 0; t < 2; ++t)
        #pragma unroll
        for (int r = 0; r < 4; ++r)
            out[(c * B_ + row0 + q * 4 + r) * OUT_ + nt[t]] = y[t][r];
}

extern "C" void kernel_launch(void* const* d_in, const int* in_sizes, int n_in,
                              void* d_out, int out_size, void* d_ws, size_t ws_size,
                              hipStream_t stream)
{
    const float* X  = (const float*)d_in[0];   // [B, IN]
    const float* W  = (const float*)d_in[1];   // [C, OUT, IN]
    const float* M  = (const float*)d_in[2];   // [C, OUT, OUT]
    const float* bv = (const float*)d_in[3];   // [C, OUT]
    // d_in[4] = errTrack: unused (loop provably never converges early)
    float* out = (float*)d_out;                // [C, B, OUT]
    unsigned* slots = (unsigned*)d_ws;         // 512 x u32 per-row M flags

    // Closed-form constants for the M==I fast path (fp32 dt schedule, double agg).
    const double dinv = 1.0 / (double)(1.0f + LBD2_);   // 1/1.005
    double P = 0.0, Q = 0.0;
    for (int n = 0; n < MAXITER_; ++n) {
        float dtf = fmaxf(0.05f / (1.0f + (float)n / 10.0f), 0.01f);
        double dt = (double)dtf;
        double A  = (1.0 - dt) * dinv;
        P = A * P + dinv * dt;
        Q = A * Q - dinv * (double)LBD1_;
    }

    const int blocks = C_ * (B_ / ROWS_PER_BLOCK_);   // 512, 2 per CU
    pcn_fast<<<blocks, THREADS_, 0, stream>>>(X, W, M, bv, out, slots,
                                              (float)P, (float)Q);
    pcn_fix<<<blocks, THREADS_, 0, stream>>>(X, W, M, bv, out, slots);
}